// Round 4
// baseline (174185.400 us; speedup 1.0000x reference)
//
#include <hip/hip_runtime.h>
#include <stdint.h>

#define NN 50000
#define NE 800000
#define D 128
#define NI 32
#define EI 4
#define ODIM 3
#define EPS 1e-5f

__device__ __forceinline__ uint16_t f2h(float f) {
  _Float16 h = (_Float16)f;
  return __builtin_bit_cast(uint16_t, h);
}
__device__ __forceinline__ float h2f(uint16_t u) {
  return (float)__builtin_bit_cast(_Float16, u);
}

// ---------- weight combine: Cf = W1[IN,K]@W2[K,OD] (f32 row-major); bias = b1@W2 + b2 ----------
__global__ void k_combine(const float* __restrict__ W1, const float* __restrict__ b1,
                          const float* __restrict__ W2, const float* __restrict__ b2,
                          int IN, int K, int OD, float* __restrict__ Cf,
                          float* __restrict__ bout) {
  int tid = blockIdx.x * 256 + threadIdx.x;
  int total = (IN + 1) * OD;
  if (tid >= total) return;
  int i = tid / OD, j = tid - i * OD;
  const float* row = (i < IN) ? (W1 + (size_t)i * K) : b1;
  float acc = 0.f;
  for (int k = 0; k < K; ++k) acc += row[k] * W2[(size_t)k * OD + j];
  if (i == IN) bout[j] = acc + b2[j];
  else Cf[(size_t)i * OD + j] = acc;
}

__global__ void k_zero(float* __restrict__ p, long n) {
  long i = (long)blockIdx.x * 256 + threadIdx.x;
  if (i < n) p[i] = 0.f;
}

__global__ void k_count(const int* __restrict__ recv, float* __restrict__ cnt) {
  int i = blockIdx.x * 256 + threadIdx.x;
  if (i < NE) atomicAdd(&cnt[recv[i]], 1.f);
}

// 64-wide dot-accumulate: broadcast rr across lanes; lane owns output cols 2*lane, 2*lane+1
__device__ __forceinline__ void seg64(float rr, const uint32_t* Wp, int base, int lane,
                                      float& a0, float& a1) {
#pragma unroll
  for (int kk = 0; kk < 64; ++kk) {
    float iv = __shfl(rr, kk);
    uint32_t w = Wp[(base + kk) * 64 + lane];
    a0 += iv * h2f((uint16_t)(w & 0xFFFFu));
    a1 += iv * h2f((uint16_t)(w >> 16));
  }
}

// LayerNorm over 128 values spread 2-per-lane across the 64-lane wave
__device__ __forceinline__ void ln2(float a0, float a1, float gc0, float gc1,
                                    float be0, float be1, float& v0, float& v1) {
  float s = a0 + a1;
#pragma unroll
  for (int m = 1; m < 64; m <<= 1) s += __shfl_xor(s, m);
  float mu = s * (1.f / 128.f);
  float d0 = a0 - mu, d1 = a1 - mu;
  float q = d0 * d0 + d1 * d1;
#pragma unroll
  for (int m = 1; m < 64; m <<= 1) q += __shfl_xor(q, m);
  float rs = rsqrtf(q * (1.f / 128.f) + EPS);
  v0 = d0 * rs * gc0 + be0;
  v1 = d1 * rs * gc1 + be1;
}

// ---------- node encoder (scalar): x = LN(nf @ Cen + ben) ----------
__global__ __launch_bounds__(512) void k_node_enc_s(
    const float* __restrict__ nf, const float* __restrict__ Cf,
    const float* __restrict__ bias, const float* __restrict__ g, const float* __restrict__ be,
    float* __restrict__ x) {
  __shared__ uint32_t Wp[NI * 64];
  for (int i = threadIdx.x; i < NI * 64; i += 512) {
    int k = i >> 6, c = (i & 63) * 2;
    Wp[i] = (uint32_t)f2h(Cf[k * 128 + c]) | ((uint32_t)f2h(Cf[k * 128 + c + 1]) << 16);
  }
  __syncthreads();
  int wid = threadIdx.x >> 6, lane = threadIdx.x & 63;
  int c0 = lane * 2;
  float bc0 = bias[c0], bc1 = bias[c0 + 1];
  float gc0 = g[c0], gc1 = g[c0 + 1], be0 = be[c0], be1 = be[c0 + 1];
  for (int n = blockIdx.x * 8 + wid; n < NN; n += gridDim.x * 8) {
    float r0 = (lane < NI) ? nf[(size_t)n * NI + lane] : 0.f;
    float a0 = bc0, a1 = bc1;
#pragma unroll
    for (int kk = 0; kk < NI; ++kk) {
      float iv = __shfl(r0, kk);
      uint32_t w = Wp[kk * 64 + lane];
      a0 += iv * h2f((uint16_t)(w & 0xFFFFu));
      a1 += iv * h2f((uint16_t)(w >> 16));
    }
    float v0, v1;
    ln2(a0, a1, gc0, gc1, be0, be1, v0, v1);
    x[(size_t)n * D + c0] = v0;
    x[(size_t)n * D + c0 + 1] = v1;
  }
}

// ---------- edge encoder (scalar): e = LN(ef @ Cee + bee) fp16; agg += e ----------
__global__ __launch_bounds__(256) void k_edge_enc(
    const float* __restrict__ ef, const int* __restrict__ recv,
    const float* __restrict__ W, const float* __restrict__ bias,
    const float* __restrict__ g, const float* __restrict__ be,
    uint16_t* __restrict__ e, float* __restrict__ agg) {
  int wid = threadIdx.x >> 6, lane = threadIdx.x & 63;
  int edge = blockIdx.x * 4 + wid;
  int c0 = lane * 2, c1 = c0 + 1;
  float4 f = *(const float4*)(ef + (size_t)edge * EI);
  float h0 = bias[c0] + f.x * W[c0] + f.y * W[D + c0] + f.z * W[2 * D + c0] + f.w * W[3 * D + c0];
  float h1 = bias[c1] + f.x * W[c1] + f.y * W[D + c1] + f.z * W[2 * D + c1] + f.w * W[3 * D + c1];
  float v0, v1;
  ln2(h0, h1, g[c0], g[c1], be[c0], be[c1], v0, v1);
  *(uint32_t*)&e[(size_t)edge * D + c0] = (uint32_t)f2h(v0) | ((uint32_t)f2h(v1) << 16);
  int rv = recv[edge];
  atomicAdd(&agg[(size_t)rv * D + c0], v0);
  atomicAdd(&agg[(size_t)rv * D + c1], v1);
}

// ---------- finalize encode: x += agg/cnt; agg = 0 ----------
__global__ void k_finalize(float* __restrict__ x, float* __restrict__ agg,
                           const float* __restrict__ cnt) {
  long i = (long)blockIdx.x * 256 + threadIdx.x;
  if (i >= (long)NN * D) return;
  int row = (int)(i >> 7);
  float inv = 1.f / fmaxf(cnt[row], 1.f);
  x[i] += agg[i] * inv;
  agg[i] = 0.f;
}

// ---------- processor edge step (scalar): e_new = LN([x_r|x_s|e]@Cpe + b); e += e_new; agg += e_new ----------
__global__ __launch_bounds__(512) void k_edge_step_s(
    const float* __restrict__ x, uint16_t* __restrict__ e16,
    const int* __restrict__ recv, const int* __restrict__ send,
    const float* __restrict__ Cf, const float* __restrict__ bias,
    const float* __restrict__ g, const float* __restrict__ be,
    float* __restrict__ agg) {
  __shared__ uint32_t Wp[384 * 64];  // 96 KB: packed fp16 pairs, [k][col-pair]
  for (int i = threadIdx.x; i < 384 * 64; i += 512) {
    int k = i >> 6, c = (i & 63) * 2;
    Wp[i] = (uint32_t)f2h(Cf[(size_t)k * 128 + c]) | ((uint32_t)f2h(Cf[(size_t)k * 128 + c + 1]) << 16);
  }
  __syncthreads();
  int wid = threadIdx.x >> 6, lane = threadIdx.x & 63;
  int c0 = lane * 2;
  float bc0 = bias[c0], bc1 = bias[c0 + 1];
  float gc0 = g[c0], gc1 = g[c0 + 1], be0 = be[c0], be1 = be[c0 + 1];
  for (int edge = blockIdx.x * 8 + wid; edge < NE; edge += gridDim.x * 8) {
    int rv = recv[edge], sd = send[edge];
    const float* xr = x + (size_t)rv * D;
    const float* xs = x + (size_t)sd * D;
    float r0 = xr[lane], r1 = xr[64 + lane];
    float r2 = xs[lane], r3 = xs[64 + lane];
    float r4 = h2f(e16[(size_t)edge * D + lane]);
    float r5 = h2f(e16[(size_t)edge * D + 64 + lane]);
    float a0 = bc0, a1 = bc1;
    seg64(r0, Wp, 0, lane, a0, a1);
    seg64(r1, Wp, 64, lane, a0, a1);
    seg64(r2, Wp, 128, lane, a0, a1);
    seg64(r3, Wp, 192, lane, a0, a1);
    seg64(r4, Wp, 256, lane, a0, a1);
    seg64(r5, Wp, 320, lane, a0, a1);
    float v0, v1;
    ln2(a0, a1, gc0, gc1, be0, be1, v0, v1);
    uint32_t* ep = (uint32_t*)(e16 + (size_t)edge * D) + lane;
    uint32_t old = *ep;
    float ne0 = h2f((uint16_t)(old & 0xFFFFu)) + v0;
    float ne1 = h2f((uint16_t)(old >> 16)) + v1;
    *ep = (uint32_t)f2h(ne0) | ((uint32_t)f2h(ne1) << 16);
    atomicAdd(&agg[(size_t)rv * D + c0], v0);
    atomicAdd(&agg[(size_t)rv * D + c0 + 1], v1);
  }
}

// ---------- processor node step (scalar): x += LN([x|agg/cnt]@Cpn + b); agg = 0 ----------
__global__ __launch_bounds__(512) void k_node_step_s(
    float* __restrict__ x, float* __restrict__ agg, const float* __restrict__ cnt,
    const float* __restrict__ Cf, const float* __restrict__ bias,
    const float* __restrict__ g, const float* __restrict__ be) {
  __shared__ uint32_t Wp[256 * 64];  // 64 KB
  for (int i = threadIdx.x; i < 256 * 64; i += 512) {
    int k = i >> 6, c = (i & 63) * 2;
    Wp[i] = (uint32_t)f2h(Cf[(size_t)k * 128 + c]) | ((uint32_t)f2h(Cf[(size_t)k * 128 + c + 1]) << 16);
  }
  __syncthreads();
  int wid = threadIdx.x >> 6, lane = threadIdx.x & 63;
  int c0 = lane * 2;
  float bc0 = bias[c0], bc1 = bias[c0 + 1];
  float gc0 = g[c0], gc1 = g[c0 + 1], be0 = be[c0], be1 = be[c0 + 1];
  for (int n = blockIdx.x * 8 + wid; n < NN; n += gridDim.x * 8) {
    const float* xr = x + (size_t)n * D;
    const float* ar = agg + (size_t)n * D;
    float inv = 1.f / fmaxf(cnt[n], 1.f);
    float r0 = xr[lane], r1 = xr[64 + lane];
    float r2 = ar[lane] * inv, r3 = ar[64 + lane] * inv;
    float a0 = bc0, a1 = bc1;
    seg64(r0, Wp, 0, lane, a0, a1);
    seg64(r1, Wp, 64, lane, a0, a1);
    seg64(r2, Wp, 128, lane, a0, a1);
    seg64(r3, Wp, 192, lane, a0, a1);
    float v0, v1;
    ln2(a0, a1, gc0, gc1, be0, be1, v0, v1);
    x[(size_t)n * D + c0] += v0;
    x[(size_t)n * D + c0 + 1] += v1;
    agg[(size_t)n * D + c0] = 0.f;
    agg[(size_t)n * D + c0 + 1] = 0.f;
  }
}

// ---------- decoder: out = x @ Cde + bde (fp32) ----------
__global__ __launch_bounds__(256) void k_decode(
    const float* __restrict__ x, const float* __restrict__ Wd, const float* __restrict__ bd,
    float* __restrict__ out) {
  __shared__ float W[D * ODIM];
  __shared__ float b[ODIM];
  for (int i = threadIdx.x; i < D * ODIM; i += 256) W[i] = Wd[i];
  if (threadIdx.x < ODIM) b[threadIdx.x] = bd[threadIdx.x];
  __syncthreads();
  int node = blockIdx.x * 256 + threadIdx.x;
  if (node >= NN) return;
  const float* xr = x + (size_t)node * D;
  float a0 = b[0], a1 = b[1], a2 = b[2];
#pragma unroll 4
  for (int k = 0; k < D; k += 4) {
    float4 xv = *(const float4*)(xr + k);
    a0 += xv.x * W[k * 3]     + xv.y * W[(k + 1) * 3]     + xv.z * W[(k + 2) * 3]     + xv.w * W[(k + 3) * 3];
    a1 += xv.x * W[k * 3 + 1] + xv.y * W[(k + 1) * 3 + 1] + xv.z * W[(k + 2) * 3 + 1] + xv.w * W[(k + 3) * 3 + 1];
    a2 += xv.x * W[k * 3 + 2] + xv.y * W[(k + 1) * 3 + 2] + xv.z * W[(k + 2) * 3 + 2] + xv.w * W[(k + 3) * 3 + 2];
  }
  out[(size_t)node * 3] = a0;
  out[(size_t)node * 3 + 1] = a1;
  out[(size_t)node * 3 + 2] = a2;
}

extern "C" void kernel_launch(void* const* d_in, const int* in_sizes, int n_in,
                              void* d_out, int out_size, void* d_ws, size_t ws_size,
                              hipStream_t stream) {
  (void)in_sizes; (void)n_in; (void)out_size; (void)ws_size;
  const float* node_feat = (const float*)d_in[0];
  const float* edge_feat = (const float*)d_in[1];
  const int* eidx = (const int*)d_in[2];
  const int* recv = eidx;
  const int* send = eidx + NE;
  const float* en_W1 = (const float*)d_in[3];  const float* en_b1 = (const float*)d_in[4];
  const float* en_W2 = (const float*)d_in[5];  const float* en_b2 = (const float*)d_in[6];
  const float* en_g  = (const float*)d_in[7];  const float* en_be = (const float*)d_in[8];
  const float* ee_W1 = (const float*)d_in[9];  const float* ee_b1 = (const float*)d_in[10];
  const float* ee_W2 = (const float*)d_in[11]; const float* ee_b2 = (const float*)d_in[12];
  const float* ee_g  = (const float*)d_in[13]; const float* ee_be = (const float*)d_in[14];
  const float* pe_W1 = (const float*)d_in[15]; const float* pe_b1 = (const float*)d_in[16];
  const float* pe_W2 = (const float*)d_in[17]; const float* pe_b2 = (const float*)d_in[18];
  const float* pe_g  = (const float*)d_in[19]; const float* pe_be = (const float*)d_in[20];
  const float* pn_W1 = (const float*)d_in[21]; const float* pn_b1 = (const float*)d_in[22];
  const float* pn_W2 = (const float*)d_in[23]; const float* pn_b2 = (const float*)d_in[24];
  const float* pn_g  = (const float*)d_in[25]; const float* pn_be = (const float*)d_in[26];
  const float* de_W1 = (const float*)d_in[27]; const float* de_b1 = (const float*)d_in[28];
  const float* de_W2 = (const float*)d_in[29]; const float* de_b2 = (const float*)d_in[30];

  char* ws = (char*)d_ws;
  size_t off = 0;
  auto alloc = [&](size_t bytes) -> char* {
    char* p = ws + off;
    off += (bytes + 255) & ~(size_t)255;
    return p;
  };
  // e(fp16) 204.8e6 + x 25.6e6 + agg 25.6e6 + cnt 0.2e6 + fp32 combined weights ~1.0e6  => ~257.2e6 B
  uint16_t* e   = (uint16_t*)alloc((size_t)NE * D * 2);
  float* x      = (float*)alloc((size_t)NN * D * 4);
  float* agg    = (float*)alloc((size_t)NN * D * 4);
  float* cnt    = (float*)alloc((size_t)NN * 4);
  float* Cen = (float*)alloc((size_t)32 * 128 * 4);
  float* Cee = (float*)alloc((size_t)4 * 128 * 4);
  float* Cpe = (float*)alloc((size_t)3 * 384 * 128 * 4);
  float* Cpn = (float*)alloc((size_t)3 * 256 * 128 * 4);
  float* Cde = (float*)alloc((size_t)128 * 3 * 4);
  float* ben = (float*)alloc(128 * 4);
  float* bee = (float*)alloc(128 * 4);
  float* bpe = (float*)alloc(3 * 128 * 4);
  float* bpn = (float*)alloc(3 * 128 * 4);
  float* bde = (float*)alloc(16);

  // --- combine all MLP weight pairs (linear MLPs: W1@W2, b1@W2+b2), all fp32 ---
  k_combine<<<(33 * 128 + 255) / 256, 256, 0, stream>>>(en_W1, en_b1, en_W2, en_b2, 32, 128, 128, Cen, ben);
  k_combine<<<(5 * 128 + 255) / 256, 256, 0, stream>>>(ee_W1, ee_b1, ee_W2, ee_b2, 4, 128, 128, Cee, bee);
  for (int s = 0; s < 3; ++s) {
    k_combine<<<(385 * 128 + 255) / 256, 256, 0, stream>>>(
        pe_W1 + (size_t)s * 384 * 128, pe_b1 + s * 128, pe_W2 + (size_t)s * 128 * 128, pe_b2 + s * 128,
        384, 128, 128, Cpe + (size_t)s * 384 * 128, bpe + s * 128);
    k_combine<<<(257 * 128 + 255) / 256, 256, 0, stream>>>(
        pn_W1 + (size_t)s * 256 * 128, pn_b1 + s * 128, pn_W2 + (size_t)s * 128 * 128, pn_b2 + s * 128,
        256, 128, 128, Cpn + (size_t)s * 256 * 128, bpn + s * 128);
  }
  k_combine<<<(129 * 3 + 255) / 256, 256, 0, stream>>>(de_W1, de_b1, de_W2, de_b2, 128, 128, 3, Cde, bde);

  // --- init: zero agg + cnt, count in-degrees ---
  k_zero<<<((long)NN * D + 255) / 256, 256, 0, stream>>>(agg, (long)NN * D);
  k_zero<<<(NN + 255) / 256, 256, 0, stream>>>(cnt, NN);
  k_count<<<(NE + 255) / 256, 256, 0, stream>>>(recv, cnt);

  // --- encode ---
  k_node_enc_s<<<512, 512, 0, stream>>>(node_feat, Cen, ben, en_g, en_be, x);
  k_edge_enc<<<NE / 4, 256, 0, stream>>>(edge_feat, recv, Cee, bee, ee_g, ee_be, e, agg);
  k_finalize<<<((long)NN * D + 255) / 256, 256, 0, stream>>>(x, agg, cnt);

  // --- process: 3 interaction-network steps (scalar fp32 math) ---
  for (int s = 0; s < 3; ++s) {
    k_edge_step_s<<<500, 512, 0, stream>>>(
        x, e, recv, send, Cpe + (size_t)s * 384 * 128, bpe + s * 128,
        pe_g + s * 128, pe_be + s * 128, agg);
    k_node_step_s<<<512, 512, 0, stream>>>(
        x, agg, cnt, Cpn + (size_t)s * 256 * 128, bpn + s * 128,
        pn_g + s * 128, pn_be + s * 128);
  }

  // --- decode ---
  k_decode<<<(NN + 255) / 256, 256, 0, stream>>>(x, Cde, bde, (float*)d_out);
}

// Round 8
// 4774.376 us; speedup vs baseline: 36.4834x; 36.4834x over previous
//
#include <hip/hip_runtime.h>
#include <stdint.h>

#define NN 50000
#define NE 800000
#define D 128
#define NI 32
#define EI 4
#define ODIM 3
#define EPS 1e-5f
#define HPAD 132

typedef _Float16 half8 __attribute__((ext_vector_type(8)));
typedef float f32x4 __attribute__((ext_vector_type(4)));

__device__ __forceinline__ uint16_t f2h(float f) {
  _Float16 h = (_Float16)f;
  return __builtin_bit_cast(uint16_t, h);
}
__device__ __forceinline__ float h2f(uint16_t u) {
  return (float)__builtin_bit_cast(_Float16, u);
}

// ---------- weight combine: Cf = W1[IN,K]@W2[K,OD] (f32 row-major); bias = b1@W2 + b2 ----------
__global__ void k_combine(const float* __restrict__ W1, const float* __restrict__ b1,
                          const float* __restrict__ W2, const float* __restrict__ b2,
                          int IN, int K, int OD, float* __restrict__ Cf,
                          float* __restrict__ bout) {
  int tid = blockIdx.x * 256 + threadIdx.x;
  int total = (IN + 1) * OD;
  if (tid >= total) return;
  int i = tid / OD, j = tid - i * OD;
  const float* row = (i < IN) ? (W1 + (size_t)i * K) : b1;
  float acc = 0.f;
  for (int k = 0; k < K; ++k) acc += row[k] * W2[(size_t)k * OD + j];
  if (i == IN) bout[j] = acc + b2[j];
  else Cf[(size_t)i * OD + j] = acc;
}

// ---------- pack fp32 [IN][128] -> fp16 transposed [128][IN], nstep steps ----------
__global__ void k_pack16(const float* __restrict__ Cf, uint16_t* __restrict__ WT,
                         int IN, int nstep) {
  int idx = blockIdx.x * 256 + threadIdx.x;
  int per = IN * 128;
  if (idx >= nstep * per) return;
  int s = idx / per, rem = idx - s * per;
  int j = rem / IN, i = rem - j * IN;   // j = out col (0..127), i = in row (0..IN-1)
  WT[(size_t)s * per + (size_t)j * IN + i] = f2h(Cf[(size_t)s * per + (size_t)i * 128 + j]);
}

__global__ void k_zero(float* __restrict__ p, long n) {
  long i = (long)blockIdx.x * 256 + threadIdx.x;
  if (i < n) p[i] = 0.f;
}

__global__ void k_count(const int* __restrict__ recv, float* __restrict__ cnt) {
  int i = blockIdx.x * 256 + threadIdx.x;
  if (i < NE) atomicAdd(&cnt[recv[i]], 1.f);
}

// LayerNorm over 128 values spread 2-per-lane across the 64-lane wave
__device__ __forceinline__ void ln2(float a0, float a1, float gc0, float gc1,
                                    float be0, float be1, float& v0, float& v1) {
  float s = a0 + a1;
#pragma unroll
  for (int m = 1; m < 64; m <<= 1) s += __shfl_xor(s, m);
  float mu = s * (1.f / 128.f);
  float d0 = a0 - mu, d1 = a1 - mu;
  float q = d0 * d0 + d1 * d1;
#pragma unroll
  for (int m = 1; m < 64; m <<= 1) q += __shfl_xor(q, m);
  float rs = rsqrtf(q * (1.f / 128.f) + EPS);
  v0 = d0 * rs * gc0 + be0;
  v1 = d1 * rs * gc1 + be1;
}

__device__ __forceinline__ half8 cvt8(const float* p) {
  float4 p0 = *(const float4*)p;
  float4 p1 = *(const float4*)(p + 4);
  half8 a;
  a[0] = (_Float16)p0.x; a[1] = (_Float16)p0.y; a[2] = (_Float16)p0.z; a[3] = (_Float16)p0.w;
  a[4] = (_Float16)p1.x; a[5] = (_Float16)p1.y; a[6] = (_Float16)p1.z; a[7] = (_Float16)p1.w;
  return a;
}

// runtime C/D layout probe: measure which (A-lane row, B-lane col) feeds each acc slot.
// Exact in fp16/fp32; invariant to internal k-permutation (cancels between A and B).
__device__ __forceinline__ void probe_layout(int lanelo, int* rof, int* cof) {
  f32x4 zz = {0.f, 0.f, 0.f, 0.f};
  half8 pa, pb;
#pragma unroll
  for (int j = 0; j < 8; ++j) { pa[j] = (_Float16)(float)lanelo; pb[j] = (_Float16)(1.f / 32.f); }
  f32x4 accR = __builtin_amdgcn_mfma_f32_16x16x32_f16(pa, pb, zz, 0, 0, 0);
#pragma unroll
  for (int j = 0; j < 8; ++j) { pa[j] = (_Float16)(1.f / 32.f); pb[j] = (_Float16)(float)lanelo; }
  f32x4 accC = __builtin_amdgcn_mfma_f32_16x16x32_f16(pa, pb, zz, 0, 0, 0);
#pragma unroll
  for (int r = 0; r < 4; ++r) {
    rof[r] = ((int)(accR[r] + 0.5f)) & 15;
    cof[r] = ((int)(accC[r] + 0.5f)) & 15;
  }
}

// ---------- node encoder (scalar, proven): x = LN(nf @ Cen + ben) ----------
__global__ __launch_bounds__(512) void k_node_enc_s(
    const float* __restrict__ nf, const float* __restrict__ Cf,
    const float* __restrict__ bias, const float* __restrict__ g, const float* __restrict__ be,
    float* __restrict__ x) {
  __shared__ uint32_t Wp[NI * 64];
  for (int i = threadIdx.x; i < NI * 64; i += 512) {
    int k = i >> 6, c = (i & 63) * 2;
    Wp[i] = (uint32_t)f2h(Cf[k * 128 + c]) | ((uint32_t)f2h(Cf[k * 128 + c + 1]) << 16);
  }
  __syncthreads();
  int wid = threadIdx.x >> 6, lane = threadIdx.x & 63;
  int c0 = lane * 2;
  float bc0 = bias[c0], bc1 = bias[c0 + 1];
  float gc0 = g[c0], gc1 = g[c0 + 1], be0 = be[c0], be1 = be[c0 + 1];
  for (int n = blockIdx.x * 8 + wid; n < NN; n += gridDim.x * 8) {
    float r0 = (lane < NI) ? nf[(size_t)n * NI + lane] : 0.f;
    float a0 = bc0, a1 = bc1;
#pragma unroll
    for (int kk = 0; kk < NI; ++kk) {
      float iv = __shfl(r0, kk);
      uint32_t w = Wp[kk * 64 + lane];
      a0 += iv * h2f((uint16_t)(w & 0xFFFFu));
      a1 += iv * h2f((uint16_t)(w >> 16));
    }
    float v0, v1;
    ln2(a0, a1, gc0, gc1, be0, be1, v0, v1);
    x[(size_t)n * D + c0] = v0;
    x[(size_t)n * D + c0 + 1] = v1;
  }
}

// ---------- edge encoder (scalar, proven): e = LN(ef @ Cee + bee) fp16; agg += e ----------
__global__ __launch_bounds__(256) void k_edge_enc(
    const float* __restrict__ ef, const int* __restrict__ recv,
    const float* __restrict__ W, const float* __restrict__ bias,
    const float* __restrict__ g, const float* __restrict__ be,
    uint16_t* __restrict__ e, float* __restrict__ agg) {
  int wid = threadIdx.x >> 6, lane = threadIdx.x & 63;
  int edge = blockIdx.x * 4 + wid;
  int c0 = lane * 2, c1 = c0 + 1;
  float4 f = *(const float4*)(ef + (size_t)edge * EI);
  float h0 = bias[c0] + f.x * W[c0] + f.y * W[D + c0] + f.z * W[2 * D + c0] + f.w * W[3 * D + c0];
  float h1 = bias[c1] + f.x * W[c1] + f.y * W[D + c1] + f.z * W[2 * D + c1] + f.w * W[3 * D + c1];
  float v0, v1;
  ln2(h0, h1, g[c0], g[c1], be[c0], be[c1], v0, v1);
  *(uint32_t*)&e[(size_t)edge * D + c0] = (uint32_t)f2h(v0) | ((uint32_t)f2h(v1) << 16);
  int rv = recv[edge];
  atomicAdd(&agg[(size_t)rv * D + c0], v0);
  atomicAdd(&agg[(size_t)rv * D + c1], v1);
}

// ---------- finalize encode: x += agg/cnt; agg = 0 ----------
__global__ void k_finalize(float* __restrict__ x, float* __restrict__ agg,
                           const float* __restrict__ cnt) {
  long i = (long)blockIdx.x * 256 + threadIdx.x;
  if (i >= (long)NN * D) return;
  int row = (int)(i >> 7);
  float inv = 1.f / fmaxf(cnt[row], 1.f);
  x[i] += agg[i] * inv;
  agg[i] = 0.f;
}

// ---------- processor edge step (MFMA, self-calibrating C/D layout) ----------
// e_new = LN([x_r|x_s|e]@Cpe + b); e += e_new; agg += e_new
__global__ __launch_bounds__(256) void k_edge_step_m(
    const float* __restrict__ x, uint16_t* __restrict__ e16,
    const int* __restrict__ recv, const int* __restrict__ send,
    const uint16_t* __restrict__ WT, const float* __restrict__ bias,
    const float* __restrict__ g, const float* __restrict__ be,
    float* __restrict__ agg) {
  __shared__ float hsm[4][16][HPAD];
  int wid = threadIdx.x >> 6, lane = threadIdx.x & 63;
  int lanelo = lane & 15, kgrp = lane >> 4;
  int rof[4], cof[4];
  probe_layout(lanelo, rof, cof);

  int ebase = blockIdx.x * 64 + wid * 16;
  int myedge = ebase + lanelo;
  int rv = recv[myedge], sd = send[myedge];
  const float* a0 = x + (size_t)rv * D + kgrp * 8;
  const float* a1 = x + (size_t)sd * D + kgrp * 8;
  const uint16_t* a2 = e16 + (size_t)myedge * D + kgrp * 8;
  const uint16_t* wbase = WT + (size_t)lanelo * 384 + kgrp * 8;
  f32x4 acc[8] = {};
#pragma unroll
  for (int kk = 0; kk < 4; ++kk) {
    half8 af = cvt8(a0 + kk * 32);
#pragma unroll
    for (int nt = 0; nt < 8; ++nt) {
      half8 bf = *(const half8*)(wbase + (size_t)nt * 16 * 384 + kk * 32);
      acc[nt] = __builtin_amdgcn_mfma_f32_16x16x32_f16(af, bf, acc[nt], 0, 0, 0);
    }
  }
#pragma unroll
  for (int kk = 0; kk < 4; ++kk) {
    half8 af = cvt8(a1 + kk * 32);
#pragma unroll
    for (int nt = 0; nt < 8; ++nt) {
      half8 bf = *(const half8*)(wbase + (size_t)nt * 16 * 384 + 128 + kk * 32);
      acc[nt] = __builtin_amdgcn_mfma_f32_16x16x32_f16(af, bf, acc[nt], 0, 0, 0);
    }
  }
#pragma unroll
  for (int kk = 0; kk < 4; ++kk) {
    half8 af = *(const half8*)(a2 + kk * 32);
#pragma unroll
    for (int nt = 0; nt < 8; ++nt) {
      half8 bf = *(const half8*)(wbase + (size_t)nt * 16 * 384 + 256 + kk * 32);
      acc[nt] = __builtin_amdgcn_mfma_f32_16x16x32_f16(af, bf, acc[nt], 0, 0, 0);
    }
  }

  // scatter h = acc + bias into LDS at calibrated (row, col)
#pragma unroll
  for (int nt = 0; nt < 8; ++nt) {
#pragma unroll
    for (int r = 0; r < 4; ++r) {
      int c = nt * 16 + cof[r];
      hsm[wid][rof[r]][c] = acc[nt][r] + bias[c];
    }
  }
  __syncthreads();

  // per-row LN + writeback (same math as the proven scalar path)
  int c0 = lane * 2;
  float gc0 = g[c0], gc1 = g[c0 + 1], be0 = be[c0], be1 = be[c0 + 1];
#pragma unroll 1
  for (int i = 0; i < 16; ++i) {
    int eg = ebase + i;
    int rvi = recv[eg];
    float2 v = *(float2*)&hsm[wid][i][c0];
    float v0, v1;
    ln2(v.x, v.y, gc0, gc1, be0, be1, v0, v1);
    uint32_t* ep = (uint32_t*)(e16 + (size_t)eg * D) + lane;
    uint32_t old = *ep;
    float ne0 = h2f((uint16_t)(old & 0xFFFFu)) + v0;
    float ne1 = h2f((uint16_t)(old >> 16)) + v1;
    *ep = (uint32_t)f2h(ne0) | ((uint32_t)f2h(ne1) << 16);
    atomicAdd(&agg[(size_t)rvi * D + c0], v0);
    atomicAdd(&agg[(size_t)rvi * D + c0 + 1], v1);
  }
}

// ---------- processor node step (MFMA, same calibrated machinery) ----------
// x += LN([x|agg/cnt]@Cpn + b); agg = 0
__global__ __launch_bounds__(256) void k_node_step_m(
    float* __restrict__ x, float* __restrict__ agg, const float* __restrict__ cnt,
    const uint16_t* __restrict__ WT, const float* __restrict__ bias,
    const float* __restrict__ g, const float* __restrict__ be) {
  __shared__ float hsm[4][16][HPAD];
  int wid = threadIdx.x >> 6, lane = threadIdx.x & 63;
  int lanelo = lane & 15, kgrp = lane >> 4;
  int rof[4], cof[4];
  probe_layout(lanelo, rof, cof);

  int nbase = blockIdx.x * 64 + wid * 16;
  int nc = min(nbase + lanelo, NN - 1);
  float inv = 1.f / fmaxf(cnt[nc], 1.f);
  const float* xr = x + (size_t)nc * D + kgrp * 8;
  const float* ar = agg + (size_t)nc * D + kgrp * 8;
  const uint16_t* wbase = WT + (size_t)lanelo * 256 + kgrp * 8;
  f32x4 acc[8] = {};
#pragma unroll
  for (int kk = 0; kk < 4; ++kk) {
    half8 af = cvt8(xr + kk * 32);
#pragma unroll
    for (int nt = 0; nt < 8; ++nt) {
      half8 bf = *(const half8*)(wbase + (size_t)nt * 16 * 256 + kk * 32);
      acc[nt] = __builtin_amdgcn_mfma_f32_16x16x32_f16(af, bf, acc[nt], 0, 0, 0);
    }
  }
#pragma unroll
  for (int kk = 0; kk < 4; ++kk) {
    float4 p0 = *(const float4*)(ar + kk * 32);
    float4 p1 = *(const float4*)(ar + kk * 32 + 4);
    half8 af;
    af[0] = (_Float16)(p0.x * inv); af[1] = (_Float16)(p0.y * inv);
    af[2] = (_Float16)(p0.z * inv); af[3] = (_Float16)(p0.w * inv);
    af[4] = (_Float16)(p1.x * inv); af[5] = (_Float16)(p1.y * inv);
    af[6] = (_Float16)(p1.z * inv); af[7] = (_Float16)(p1.w * inv);
#pragma unroll
    for (int nt = 0; nt < 8; ++nt) {
      half8 bf = *(const half8*)(wbase + (size_t)nt * 16 * 256 + 128 + kk * 32);
      acc[nt] = __builtin_amdgcn_mfma_f32_16x16x32_f16(af, bf, acc[nt], 0, 0, 0);
    }
  }

#pragma unroll
  for (int nt = 0; nt < 8; ++nt) {
#pragma unroll
    for (int r = 0; r < 4; ++r) {
      int c = nt * 16 + cof[r];
      hsm[wid][rof[r]][c] = acc[nt][r] + bias[c];
    }
  }
  __syncthreads();

  int c0 = lane * 2;
  float gc0 = g[c0], gc1 = g[c0 + 1], be0 = be[c0], be1 = be[c0 + 1];
#pragma unroll 1
  for (int i = 0; i < 16; ++i) {
    int ni = nbase + i;
    if (ni >= NN) break;
    float2 v = *(float2*)&hsm[wid][i][c0];
    float v0, v1;
    ln2(v.x, v.y, gc0, gc1, be0, be1, v0, v1);
    x[(size_t)ni * D + c0] += v0;
    x[(size_t)ni * D + c0 + 1] += v1;
    agg[(size_t)ni * D + c0] = 0.f;
    agg[(size_t)ni * D + c0 + 1] = 0.f;
  }
}

// ---------- decoder: out = x @ Cde + bde (fp32) ----------
__global__ __launch_bounds__(256) void k_decode(
    const float* __restrict__ x, const float* __restrict__ Wd, const float* __restrict__ bd,
    float* __restrict__ out) {
  __shared__ float W[D * ODIM];
  __shared__ float b[ODIM];
  for (int i = threadIdx.x; i < D * ODIM; i += 256) W[i] = Wd[i];
  if (threadIdx.x < ODIM) b[threadIdx.x] = bd[threadIdx.x];
  __syncthreads();
  int node = blockIdx.x * 256 + threadIdx.x;
  if (node >= NN) return;
  const float* xr = x + (size_t)node * D;
  float a0 = b[0], a1 = b[1], a2 = b[2];
#pragma unroll 4
  for (int k = 0; k < D; k += 4) {
    float4 xv = *(const float4*)(xr + k);
    a0 += xv.x * W[k * 3]     + xv.y * W[(k + 1) * 3]     + xv.z * W[(k + 2) * 3]     + xv.w * W[(k + 3) * 3];
    a1 += xv.x * W[k * 3 + 1] + xv.y * W[(k + 1) * 3 + 1] + xv.z * W[(k + 2) * 3 + 1] + xv.w * W[(k + 3) * 3 + 1];
    a2 += xv.x * W[k * 3 + 2] + xv.y * W[(k + 1) * 3 + 2] + xv.z * W[(k + 2) * 3 + 2] + xv.w * W[(k + 3) * 3 + 2];
  }
  out[(size_t)node * 3] = a0;
  out[(size_t)node * 3 + 1] = a1;
  out[(size_t)node * 3 + 2] = a2;
}

extern "C" void kernel_launch(void* const* d_in, const int* in_sizes, int n_in,
                              void* d_out, int out_size, void* d_ws, size_t ws_size,
                              hipStream_t stream) {
  (void)in_sizes; (void)n_in; (void)out_size; (void)ws_size;
  const float* node_feat = (const float*)d_in[0];
  const float* edge_feat = (const float*)d_in[1];
  const int* eidx = (const int*)d_in[2];
  const int* recv = eidx;
  const int* send = eidx + NE;
  const float* en_W1 = (const float*)d_in[3];  const float* en_b1 = (const float*)d_in[4];
  const float* en_W2 = (const float*)d_in[5];  const float* en_b2 = (const float*)d_in[6];
  const float* en_g  = (const float*)d_in[7];  const float* en_be = (const float*)d_in[8];
  const float* ee_W1 = (const float*)d_in[9];  const float* ee_b1 = (const float*)d_in[10];
  const float* ee_W2 = (const float*)d_in[11]; const float* ee_b2 = (const float*)d_in[12];
  const float* ee_g  = (const float*)d_in[13]; const float* ee_be = (const float*)d_in[14];
  const float* pe_W1 = (const float*)d_in[15]; const float* pe_b1 = (const float*)d_in[16];
  const float* pe_W2 = (const float*)d_in[17]; const float* pe_b2 = (const float*)d_in[18];
  const float* pe_g  = (const float*)d_in[19]; const float* pe_be = (const float*)d_in[20];
  const float* pn_W1 = (const float*)d_in[21]; const float* pn_b1 = (const float*)d_in[22];
  const float* pn_W2 = (const float*)d_in[23]; const float* pn_b2 = (const float*)d_in[24];
  const float* pn_g  = (const float*)d_in[25]; const float* pn_be = (const float*)d_in[26];
  const float* de_W1 = (const float*)d_in[27]; const float* de_b1 = (const float*)d_in[28];
  const float* de_W2 = (const float*)d_in[29]; const float* de_b2 = (const float*)d_in[30];

  char* ws = (char*)d_ws;
  size_t off = 0;
  auto alloc = [&](size_t bytes) -> char* {
    char* p = ws + off;
    off += (bytes + 255) & ~(size_t)255;
    return p;
  };
  // e 204.8 + x 25.6 + agg 25.6 + cnt 0.2 + weights ~1.7  => ~258 MB < 256 MiB
  uint16_t* e   = (uint16_t*)alloc((size_t)NE * D * 2);
  float* x      = (float*)alloc((size_t)NN * D * 4);
  float* agg    = (float*)alloc((size_t)NN * D * 4);
  float* cnt    = (float*)alloc((size_t)NN * 4);
  float* Cen = (float*)alloc((size_t)32 * 128 * 4);
  float* Cee = (float*)alloc((size_t)4 * 128 * 4);
  float* Cpe = (float*)alloc((size_t)3 * 384 * 128 * 4);
  float* Cpn = (float*)alloc((size_t)3 * 256 * 128 * 4);
  float* Cde = (float*)alloc((size_t)128 * 3 * 4);
  uint16_t* WpeT = (uint16_t*)alloc((size_t)3 * 128 * 384 * 2);
  uint16_t* WpnT = (uint16_t*)alloc((size_t)3 * 128 * 256 * 2);
  float* ben = (float*)alloc(128 * 4);
  float* bee = (float*)alloc(128 * 4);
  float* bpe = (float*)alloc(3 * 128 * 4);
  float* bpn = (float*)alloc(3 * 128 * 4);
  float* bde = (float*)alloc(16);

  // --- combine all MLP weight pairs (linear MLPs: W1@W2, b1@W2+b2), fp32 ---
  k_combine<<<(33 * 128 + 255) / 256, 256, 0, stream>>>(en_W1, en_b1, en_W2, en_b2, 32, 128, 128, Cen, ben);
  k_combine<<<(5 * 128 + 255) / 256, 256, 0, stream>>>(ee_W1, ee_b1, ee_W2, ee_b2, 4, 128, 128, Cee, bee);
  for (int s = 0; s < 3; ++s) {
    k_combine<<<(385 * 128 + 255) / 256, 256, 0, stream>>>(
        pe_W1 + (size_t)s * 384 * 128, pe_b1 + s * 128, pe_W2 + (size_t)s * 128 * 128, pe_b2 + s * 128,
        384, 128, 128, Cpe + (size_t)s * 384 * 128, bpe + s * 128);
    k_combine<<<(257 * 128 + 255) / 256, 256, 0, stream>>>(
        pn_W1 + (size_t)s * 256 * 128, pn_b1 + s * 128, pn_W2 + (size_t)s * 128 * 128, pn_b2 + s * 128,
        256, 128, 128, Cpn + (size_t)s * 256 * 128, bpn + s * 128);
  }
  k_combine<<<(129 * 3 + 255) / 256, 256, 0, stream>>>(de_W1, de_b1, de_W2, de_b2, 128, 128, 3, Cde, bde);
  // pack pe/pn weights to fp16 transposed [col][k] for MFMA B-fragments
  k_pack16<<<(3 * 384 * 128 + 255) / 256, 256, 0, stream>>>(Cpe, WpeT, 384, 3);
  k_pack16<<<(3 * 256 * 128 + 255) / 256, 256, 0, stream>>>(Cpn, WpnT, 256, 3);

  // --- init: zero agg + cnt, count in-degrees ---
  k_zero<<<((long)NN * D + 255) / 256, 256, 0, stream>>>(agg, (long)NN * D);
  k_zero<<<(NN + 255) / 256, 256, 0, stream>>>(cnt, NN);
  k_count<<<(NE + 255) / 256, 256, 0, stream>>>(recv, cnt);

  // --- encode ---
  k_node_enc_s<<<512, 512, 0, stream>>>(node_feat, Cen, ben, en_g, en_be, x);
  k_edge_enc<<<NE / 4, 256, 0, stream>>>(edge_feat, recv, Cee, bee, ee_g, ee_be, e, agg);
  k_finalize<<<((long)NN * D + 255) / 256, 256, 0, stream>>>(x, agg, cnt);

  // --- process: 3 interaction-network steps ---
  for (int s = 0; s < 3; ++s) {
    k_edge_step_m<<<NE / 64, 256, 0, stream>>>(
        x, e, recv, send, WpeT + (size_t)s * 128 * 384, bpe + s * 128,
        pe_g + s * 128, pe_be + s * 128, agg);
    k_node_step_m<<<(NN + 63) / 64, 256, 0, stream>>>(
        x, agg, cnt, WpnT + (size_t)s * 128 * 256, bpn + s * 128,
        pn_g + s * 128, pn_be + s * 128);
  }

  // --- decode ---
  k_decode<<<(NN + 255) / 256, 256, 0, stream>>>(x, Cde, bde, (float*)d_out);
}

// Round 10
// 3416.317 us; speedup vs baseline: 50.9863x; 1.3975x over previous
//
#include <hip/hip_runtime.h>
#include <stdint.h>

#define NN 50000
#define NE 800000
#define D 128
#define NI 32
#define EI 4
#define ODIM 3
#define EPS 1e-5f
#define HPAD 132

typedef _Float16 half8 __attribute__((ext_vector_type(8)));
typedef float f32x4 __attribute__((ext_vector_type(4)));

__device__ __forceinline__ uint16_t f2h(float f) {
  _Float16 h = (_Float16)f;
  return __builtin_bit_cast(uint16_t, h);
}
__device__ __forceinline__ float h2f(uint16_t u) {
  return (float)__builtin_bit_cast(_Float16, u);
}
__device__ __forceinline__ uint32_t pack2(float v0, float v1) {
  return (uint32_t)f2h(v0) | ((uint32_t)f2h(v1) << 16);
}

// bijective XCD-aware block swizzle (m204 form): contiguous work chunk per XCD
__device__ __forceinline__ int xcd_swz(int bid, int nwg) {
  int q = nwg >> 3, r = nwg & 7;
  int xcd = bid & 7, loc = bid >> 3;
  return (xcd < r ? xcd * (q + 1) : r * (q + 1) + (xcd - r) * q) + loc;
}

// ---------- weight combine: Cf = W1[IN,K]@W2[K,OD] (f32 row-major); bias = b1@W2 + b2 ----------
__global__ void k_combine(const float* __restrict__ W1, const float* __restrict__ b1,
                          const float* __restrict__ W2, const float* __restrict__ b2,
                          int IN, int K, int OD, float* __restrict__ Cf,
                          float* __restrict__ bout) {
  int tid = blockIdx.x * 256 + threadIdx.x;
  int total = (IN + 1) * OD;
  if (tid >= total) return;
  int i = tid / OD, j = tid - i * OD;
  const float* row = (i < IN) ? (W1 + (size_t)i * K) : b1;
  float acc = 0.f;
  for (int k = 0; k < K; ++k) acc += row[k] * W2[(size_t)k * OD + j];
  if (i == IN) bout[j] = acc + b2[j];
  else Cf[(size_t)i * OD + j] = acc;
}

// ---------- pack fp32 [IN][128] -> fp16 transposed [128][IN], nstep steps ----------
__global__ void k_pack16(const float* __restrict__ Cf, uint16_t* __restrict__ WT,
                         int IN, int nstep) {
  int idx = blockIdx.x * 256 + threadIdx.x;
  int per = IN * 128;
  if (idx >= nstep * per) return;
  int s = idx / per, rem = idx - s * per;
  int j = rem / IN, i = rem - j * IN;
  WT[(size_t)s * per + (size_t)j * IN + i] = f2h(Cf[(size_t)s * per + (size_t)i * 128 + j]);
}

__global__ void k_zero(float* __restrict__ p, long n) {
  long i = (long)blockIdx.x * 256 + threadIdx.x;
  if (i < n) p[i] = 0.f;
}
__global__ void k_zeroi(int* __restrict__ p, long n) {
  long i = (long)blockIdx.x * 256 + threadIdx.x;
  if (i < n) p[i] = 0;
}

__global__ void k_counti(const int* __restrict__ recv, int* __restrict__ cnti) {
  int i = blockIdx.x * 256 + threadIdx.x;
  if (i < NE) atomicAdd(&cnti[recv[i]], 1);
}

// single-block exclusive scan over cnti -> rownext (ticket base); also cntf
__global__ __launch_bounds__(1024) void k_scan(const int* __restrict__ cnti,
                                               int* __restrict__ rownext,
                                               float* __restrict__ cntf) {
  __shared__ int sm[1024];
  __shared__ int basesm;
  if (threadIdx.x == 0) basesm = 0;
  __syncthreads();
  int nchunk = (NN + 1023) / 1024;
  for (int c = 0; c < nchunk; ++c) {
    int idx = c * 1024 + threadIdx.x;
    int v = (idx < NN) ? cnti[idx] : 0;
    sm[threadIdx.x] = v;
    __syncthreads();
    for (int off = 1; off < 1024; off <<= 1) {
      int t = (threadIdx.x >= off) ? sm[threadIdx.x - off] : 0;
      __syncthreads();
      sm[threadIdx.x] += t;
      __syncthreads();
    }
    int incl = sm[threadIdx.x];
    int base = basesm;
    if (idx < NN) {
      rownext[idx] = base + incl - v;
      cntf[idx] = (float)v;
    }
    __syncthreads();
    if (threadIdx.x == 1023) basesm = base + incl;
    __syncthreads();
  }
}

// ticketed scatter: perm[pos] = edge id, sorted by recv
__global__ void k_perm(const int* __restrict__ recv, int* __restrict__ rownext,
                       int* __restrict__ perm) {
  int i = blockIdx.x * 256 + threadIdx.x;
  if (i < NE) {
    int pos = atomicAdd(&rownext[recv[i]], 1);
    perm[pos] = i;
  }
}

// LayerNorm over 128 values spread 2-per-lane across the 64-lane wave
__device__ __forceinline__ void ln2(float a0, float a1, float gc0, float gc1,
                                    float be0, float be1, float& v0, float& v1) {
  float s = a0 + a1;
#pragma unroll
  for (int m = 1; m < 64; m <<= 1) s += __shfl_xor(s, m);
  float mu = s * (1.f / 128.f);
  float d0 = a0 - mu, d1 = a1 - mu;
  float q = d0 * d0 + d1 * d1;
#pragma unroll
  for (int m = 1; m < 64; m <<= 1) q += __shfl_xor(q, m);
  float rs = rsqrtf(q * (1.f / 128.f) + EPS);
  v0 = d0 * rs * gc0 + be0;
  v1 = d1 * rs * gc1 + be1;
}

__device__ __forceinline__ half8 cvt8(const float* p) {
  float4 p0 = *(const float4*)p;
  float4 p1 = *(const float4*)(p + 4);
  half8 a;
  a[0] = (_Float16)p0.x; a[1] = (_Float16)p0.y; a[2] = (_Float16)p0.z; a[3] = (_Float16)p0.w;
  a[4] = (_Float16)p1.x; a[5] = (_Float16)p1.y; a[6] = (_Float16)p1.z; a[7] = (_Float16)p1.w;
  return a;
}

// runtime C/D layout probe (proven r8): which (A-row, B-col) feeds each acc slot
__device__ __forceinline__ void probe_layout(int lanelo, int* rof, int* cof) {
  f32x4 zz = {0.f, 0.f, 0.f, 0.f};
  half8 pa, pb;
#pragma unroll
  for (int j = 0; j < 8; ++j) { pa[j] = (_Float16)(float)lanelo; pb[j] = (_Float16)(1.f / 32.f); }
  f32x4 accR = __builtin_amdgcn_mfma_f32_16x16x32_f16(pa, pb, zz, 0, 0, 0);
#pragma unroll
  for (int j = 0; j < 8; ++j) { pa[j] = (_Float16)(1.f / 32.f); pb[j] = (_Float16)(float)lanelo; }
  f32x4 accC = __builtin_amdgcn_mfma_f32_16x16x32_f16(pa, pb, zz, 0, 0, 0);
#pragma unroll
  for (int r = 0; r < 4; ++r) {
    rof[r] = ((int)(accR[r] + 0.5f)) & 15;
    cof[r] = ((int)(accC[r] + 0.5f)) & 15;
  }
}

// ---------- node encoder (MFMA): x = LN(nf @ Cen + ben) ----------
__global__ __launch_bounds__(256) void k_node_enc_m(
    const float* __restrict__ nf, const uint16_t* __restrict__ WT,
    const float* __restrict__ bias, const float* __restrict__ g, const float* __restrict__ be,
    float* __restrict__ x) {
  __shared__ float hsm[4][16][HPAD];
  int wid = threadIdx.x >> 6, lane = threadIdx.x & 63;
  int lanelo = lane & 15, kgrp = lane >> 4;
  int rof[4], cof[4];
  probe_layout(lanelo, rof, cof);
  int nbase = blockIdx.x * 64 + wid * 16;
  int nc = min(nbase + lanelo, NN - 1);
  half8 af = cvt8(nf + (size_t)nc * NI + kgrp * 8);
  f32x4 acc[8] = {};
#pragma unroll
  for (int nt = 0; nt < 8; ++nt) {
    half8 bf = *(const half8*)(WT + (size_t)(nt * 16 + lanelo) * NI + kgrp * 8);
    acc[nt] = __builtin_amdgcn_mfma_f32_16x16x32_f16(af, bf, acc[nt], 0, 0, 0);
  }
#pragma unroll
  for (int nt = 0; nt < 8; ++nt)
#pragma unroll
    for (int r = 0; r < 4; ++r) {
      int c = nt * 16 + cof[r];
      hsm[wid][rof[r]][c] = acc[nt][r] + bias[c];
    }
  __syncthreads();
  int c0 = lane * 2;
  float gc0 = g[c0], gc1 = g[c0 + 1], be0 = be[c0], be1 = be[c0 + 1];
#pragma unroll 1
  for (int i = 0; i < 16; ++i) {
    int ni = nbase + i;
    if (ni >= NN) break;
    float2 v = *(float2*)&hsm[wid][i][c0];
    float v0, v1;
    ln2(v.x, v.y, gc0, gc1, be0, be1, v0, v1);
    float2 o; o.x = v0; o.y = v1;
    *(float2*)&x[(size_t)ni * D + c0] = o;
  }
}

// ---------- edge encoder (sorted slots, run-merged atomics) ----------
// slot j holds logical edge perm[j]: e[j] = LN(ef[perm[j]] @ Cee + bee); agg[recv] += e
__global__ __launch_bounds__(256) void k_edge_enc(
    const float* __restrict__ ef, const int* __restrict__ recv, const int* __restrict__ perm,
    const float* __restrict__ W, const float* __restrict__ bias,
    const float* __restrict__ g, const float* __restrict__ be,
    uint16_t* __restrict__ e16, float* __restrict__ agg) {
  int wid = threadIdx.x >> 6, lane = threadIdx.x & 63, lanelo = lane & 15;
  int wg = xcd_swz(blockIdx.x, gridDim.x);
  int ebase = wg * 64 + wid * 16;
  int c0 = lane * 2, c1 = c0 + 1;
  int leL = perm[ebase + lanelo];
  int rvL = recv[leL];
  float w00 = W[c0], w01 = W[c1], w10 = W[D + c0], w11 = W[D + c1];
  float w20 = W[2 * D + c0], w21 = W[2 * D + c1], w30 = W[3 * D + c0], w31 = W[3 * D + c1];
  float b0 = bias[c0], b1 = bias[c1];
  float gc0 = g[c0], gc1 = g[c1], be0 = be[c0], be1 = be[c1];
  float s0 = 0.f, s1 = 0.f; int cur = -1;
#pragma unroll 1
  for (int i = 0; i < 16; ++i) {
    int le = __shfl(leL, i);
    int rv = __shfl(rvL, i);
    float4 f = *(const float4*)(ef + (size_t)le * EI);
    float h0 = b0 + f.x * w00 + f.y * w10 + f.z * w20 + f.w * w30;
    float h1 = b1 + f.x * w01 + f.y * w11 + f.z * w21 + f.w * w31;
    float v0, v1;
    ln2(h0, h1, gc0, gc1, be0, be1, v0, v1);
    *(uint32_t*)&e16[(size_t)(ebase + i) * D + c0] = pack2(v0, v1);
    if (rv != cur) {
      if (cur >= 0) {
        atomicAdd(&agg[(size_t)cur * D + c0], s0);
        atomicAdd(&agg[(size_t)cur * D + c1], s1);
      }
      cur = rv; s0 = 0.f; s1 = 0.f;
    }
    s0 += v0; s1 += v1;
  }
  atomicAdd(&agg[(size_t)cur * D + c0], s0);
  atomicAdd(&agg[(size_t)cur * D + c1], s1);
}

// ---------- finalize encode: x += agg/cnt; agg = 0 ----------
__global__ void k_finalize(float* __restrict__ x, float* __restrict__ agg,
                           const float* __restrict__ cnt) {
  long i = (long)blockIdx.x * 256 + threadIdx.x;
  if (i >= (long)NN * D) return;
  int row = (int)(i >> 7);
  float inv = 1.f / fmaxf(cnt[row], 1.f);
  x[i] += agg[i] * inv;
  agg[i] = 0.f;
}

// ---------- processor edge step (MFMA + sorted slots + run-merged atomics) ----------
__global__ __launch_bounds__(256) void k_edge_step_m(
    const float* __restrict__ x, uint16_t* __restrict__ e16,
    const int* __restrict__ recv, const int* __restrict__ send, const int* __restrict__ perm,
    const uint16_t* __restrict__ WT, const float* __restrict__ bias,
    const float* __restrict__ g, const float* __restrict__ be,
    float* __restrict__ agg) {
  __shared__ float hsm[4][16][HPAD];
  int wid = threadIdx.x >> 6, lane = threadIdx.x & 63;
  int lanelo = lane & 15, kgrp = lane >> 4;
  int rof[4], cof[4];
  probe_layout(lanelo, rof, cof);

  int wg = xcd_swz(blockIdx.x, gridDim.x);
  int ebase = wg * 64 + wid * 16;
  int j16 = ebase + lanelo;            // physical e slot
  int le = perm[j16];                  // logical edge
  int rv = recv[le], sd = send[le];
  const float* a0 = x + (size_t)rv * D + kgrp * 8;
  const float* a1 = x + (size_t)sd * D + kgrp * 8;
  const uint16_t* a2 = e16 + (size_t)j16 * D + kgrp * 8;
  const uint16_t* wbase = WT + (size_t)lanelo * 384 + kgrp * 8;
  f32x4 acc[8] = {};
#pragma unroll
  for (int kk = 0; kk < 4; ++kk) {
    half8 af = cvt8(a0 + kk * 32);
#pragma unroll
    for (int nt = 0; nt < 8; ++nt) {
      half8 bf = *(const half8*)(wbase + (size_t)nt * 16 * 384 + kk * 32);
      acc[nt] = __builtin_amdgcn_mfma_f32_16x16x32_f16(af, bf, acc[nt], 0, 0, 0);
    }
  }
#pragma unroll
  for (int kk = 0; kk < 4; ++kk) {
    half8 af = cvt8(a1 + kk * 32);
#pragma unroll
    for (int nt = 0; nt < 8; ++nt) {
      half8 bf = *(const half8*)(wbase + (size_t)nt * 16 * 384 + 128 + kk * 32);
      acc[nt] = __builtin_amdgcn_mfma_f32_16x16x32_f16(af, bf, acc[nt], 0, 0, 0);
    }
  }
#pragma unroll
  for (int kk = 0; kk < 4; ++kk) {
    half8 af = *(const half8*)(a2 + kk * 32);
#pragma unroll
    for (int nt = 0; nt < 8; ++nt) {
      half8 bf = *(const half8*)(wbase + (size_t)nt * 16 * 384 + 256 + kk * 32);
      acc[nt] = __builtin_amdgcn_mfma_f32_16x16x32_f16(af, bf, acc[nt], 0, 0, 0);
    }
  }

#pragma unroll
  for (int nt = 0; nt < 8; ++nt)
#pragma unroll
    for (int r = 0; r < 4; ++r) {
      int c = nt * 16 + cof[r];
      hsm[wid][rof[r]][c] = acc[nt][r] + bias[c];
    }
  __syncthreads();

  int c0 = lane * 2, c1 = c0 + 1;
  float gc0 = g[c0], gc1 = g[c1], be0 = be[c0], be1 = be[c1];
  float s0 = 0.f, s1 = 0.f; int cur = -1;
#pragma unroll 1
  for (int i = 0; i < 16; ++i) {
    int rvi = __shfl(rv, i);   // lanes 0..15 hold recv of edges 0..15 (kgrp dups identical)
    float2 v = *(float2*)&hsm[wid][i][c0];
    float v0, v1;
    ln2(v.x, v.y, gc0, gc1, be0, be1, v0, v1);
    uint32_t* ep = (uint32_t*)(e16 + (size_t)(ebase + i) * D) + lane;
    uint32_t old = *ep;
    float ne0 = h2f((uint16_t)(old & 0xFFFFu)) + v0;
    float ne1 = h2f((uint16_t)(old >> 16)) + v1;
    *ep = pack2(ne0, ne1);
    if (rvi != cur) {
      if (cur >= 0) {
        atomicAdd(&agg[(size_t)cur * D + c0], s0);
        atomicAdd(&agg[(size_t)cur * D + c1], s1);
      }
      cur = rvi; s0 = 0.f; s1 = 0.f;
    }
    s0 += v0; s1 += v1;
  }
  atomicAdd(&agg[(size_t)cur * D + c0], s0);
  atomicAdd(&agg[(size_t)cur * D + c1], s1);
}

// ---------- processor node step (MFMA): x += LN([x|agg/cnt]@Cpn + b); agg = 0 ----------
__global__ __launch_bounds__(256) void k_node_step_m(
    float* __restrict__ x, float* __restrict__ agg, const float* __restrict__ cnt,
    const uint16_t* __restrict__ WT, const float* __restrict__ bias,
    const float* __restrict__ g, const float* __restrict__ be) {
  __shared__ float hsm[4][16][HPAD];
  int wid = threadIdx.x >> 6, lane = threadIdx.x & 63;
  int lanelo = lane & 15, kgrp = lane >> 4;
  int rof[4], cof[4];
  probe_layout(lanelo, rof, cof);

  int nbase = blockIdx.x * 64 + wid * 16;
  int nc = min(nbase + lanelo, NN - 1);
  float inv = 1.f / fmaxf(cnt[nc], 1.f);
  const float* xr = x + (size_t)nc * D + kgrp * 8;
  const float* ar = agg + (size_t)nc * D + kgrp * 8;
  const uint16_t* wbase = WT + (size_t)lanelo * 256 + kgrp * 8;
  f32x4 acc[8] = {};
#pragma unroll
  for (int kk = 0; kk < 4; ++kk) {
    half8 af = cvt8(xr + kk * 32);
#pragma unroll
    for (int nt = 0; nt < 8; ++nt) {
      half8 bf = *(const half8*)(wbase + (size_t)nt * 16 * 256 + kk * 32);
      acc[nt] = __builtin_amdgcn_mfma_f32_16x16x32_f16(af, bf, acc[nt], 0, 0, 0);
    }
  }
#pragma unroll
  for (int kk = 0; kk < 4; ++kk) {
    float4 p0 = *(const float4*)(ar + kk * 32);
    float4 p1 = *(const float4*)(ar + kk * 32 + 4);
    half8 af;
    af[0] = (_Float16)(p0.x * inv); af[1] = (_Float16)(p0.y * inv);
    af[2] = (_Float16)(p0.z * inv); af[3] = (_Float16)(p0.w * inv);
    af[4] = (_Float16)(p1.x * inv); af[5] = (_Float16)(p1.y * inv);
    af[6] = (_Float16)(p1.z * inv); af[7] = (_Float16)(p1.w * inv);
#pragma unroll
    for (int nt = 0; nt < 8; ++nt) {
      half8 bf = *(const half8*)(wbase + (size_t)nt * 16 * 256 + 128 + kk * 32);
      acc[nt] = __builtin_amdgcn_mfma_f32_16x16x32_f16(af, bf, acc[nt], 0, 0, 0);
    }
  }

#pragma unroll
  for (int nt = 0; nt < 8; ++nt)
#pragma unroll
    for (int r = 0; r < 4; ++r) {
      int c = nt * 16 + cof[r];
      hsm[wid][rof[r]][c] = acc[nt][r] + bias[c];
    }
  __syncthreads();

  int c0 = lane * 2;
  float gc0 = g[c0], gc1 = g[c0 + 1], be0 = be[c0], be1 = be[c0 + 1];
#pragma unroll 1
  for (int i = 0; i < 16; ++i) {
    int ni = nbase + i;
    if (ni >= NN) break;
    float2 v = *(float2*)&hsm[wid][i][c0];
    float v0, v1;
    ln2(v.x, v.y, gc0, gc1, be0, be1, v0, v1);
    x[(size_t)ni * D + c0] += v0;
    x[(size_t)ni * D + c0 + 1] += v1;
    agg[(size_t)ni * D + c0] = 0.f;
    agg[(size_t)ni * D + c0 + 1] = 0.f;
  }
}

// ---------- decoder: out = x @ Cde + bde (fp32) ----------
__global__ __launch_bounds__(256) void k_decode(
    const float* __restrict__ x, const float* __restrict__ Wd, const float* __restrict__ bd,
    float* __restrict__ out) {
  __shared__ float W[D * ODIM];
  __shared__ float b[ODIM];
  for (int i = threadIdx.x; i < D * ODIM; i += 256) W[i] = Wd[i];
  if (threadIdx.x < ODIM) b[threadIdx.x] = bd[threadIdx.x];
  __syncthreads();
  int node = blockIdx.x * 256 + threadIdx.x;
  if (node >= NN) return;
  const float* xr = x + (size_t)node * D;
  float a0 = b[0], a1 = b[1], a2 = b[2];
#pragma unroll 4
  for (int k = 0; k < D; k += 4) {
    float4 xv = *(const float4*)(xr + k);
    a0 += xv.x * W[k * 3]     + xv.y * W[(k + 1) * 3]     + xv.z * W[(k + 2) * 3]     + xv.w * W[(k + 3) * 3];
    a1 += xv.x * W[k * 3 + 1] + xv.y * W[(k + 1) * 3 + 1] + xv.z * W[(k + 2) * 3 + 1] + xv.w * W[(k + 3) * 3 + 1];
    a2 += xv.x * W[k * 3 + 2] + xv.y * W[(k + 1) * 3 + 2] + xv.z * W[(k + 2) * 3 + 2] + xv.w * W[(k + 3) * 3 + 2];
  }
  out[(size_t)node * 3] = a0;
  out[(size_t)node * 3 + 1] = a1;
  out[(size_t)node * 3 + 2] = a2;
}

extern "C" void kernel_launch(void* const* d_in, const int* in_sizes, int n_in,
                              void* d_out, int out_size, void* d_ws, size_t ws_size,
                              hipStream_t stream) {
  (void)in_sizes; (void)n_in; (void)out_size; (void)ws_size;
  const float* node_feat = (const float*)d_in[0];
  const float* edge_feat = (const float*)d_in[1];
  const int* eidx = (const int*)d_in[2];
  const int* recv = eidx;
  const int* send = eidx + NE;
  const float* en_W1 = (const float*)d_in[3];  const float* en_b1 = (const float*)d_in[4];
  const float* en_W2 = (const float*)d_in[5];  const float* en_b2 = (const float*)d_in[6];
  const float* en_g  = (const float*)d_in[7];  const float* en_be = (const float*)d_in[8];
  const float* ee_W1 = (const float*)d_in[9];  const float* ee_b1 = (const float*)d_in[10];
  const float* ee_W2 = (const float*)d_in[11]; const float* ee_b2 = (const float*)d_in[12];
  const float* ee_g  = (const float*)d_in[13]; const float* ee_be = (const float*)d_in[14];
  const float* pe_W1 = (const float*)d_in[15]; const float* pe_b1 = (const float*)d_in[16];
  const float* pe_W2 = (const float*)d_in[17]; const float* pe_b2 = (const float*)d_in[18];
  const float* pe_g  = (const float*)d_in[19]; const float* pe_be = (const float*)d_in[20];
  const float* pn_W1 = (const float*)d_in[21]; const float* pn_b1 = (const float*)d_in[22];
  const float* pn_W2 = (const float*)d_in[23]; const float* pn_b2 = (const float*)d_in[24];
  const float* pn_g  = (const float*)d_in[25]; const float* pn_be = (const float*)d_in[26];
  const float* de_W1 = (const float*)d_in[27]; const float* de_b1 = (const float*)d_in[28];
  const float* de_W2 = (const float*)d_in[29]; const float* de_b2 = (const float*)d_in[30];

  char* ws = (char*)d_ws;
  size_t off = 0;
  auto alloc = [&](size_t bytes) -> char* {
    char* p = ws + off;
    off += (bytes + 255) & ~(size_t)255;
    return p;
  };
  // e 204.8 + x 25.6 + agg 25.6 + csr 3.8 + weights ~1.7  => ~262 MB < 256 MiB
  uint16_t* e   = (uint16_t*)alloc((size_t)NE * D * 2);
  float* x      = (float*)alloc((size_t)NN * D * 4);
  float* agg    = (float*)alloc((size_t)NN * D * 4);
  float* cntf   = (float*)alloc((size_t)NN * 4);
  int* cnti     = (int*)alloc((size_t)NN * 4);
  int* rownext  = (int*)alloc((size_t)NN * 4);
  int* perm     = (int*)alloc((size_t)NE * 4);
  float* Cen = (float*)alloc((size_t)32 * 128 * 4);
  float* Cee = (float*)alloc((size_t)4 * 128 * 4);
  float* Cpe = (float*)alloc((size_t)3 * 384 * 128 * 4);
  float* Cpn = (float*)alloc((size_t)3 * 256 * 128 * 4);
  float* Cde = (float*)alloc((size_t)128 * 3 * 4);
  uint16_t* WenT = (uint16_t*)alloc((size_t)128 * 32 * 2);
  uint16_t* WpeT = (uint16_t*)alloc((size_t)3 * 128 * 384 * 2);
  uint16_t* WpnT = (uint16_t*)alloc((size_t)3 * 128 * 256 * 2);
  float* ben = (float*)alloc(128 * 4);
  float* bee = (float*)alloc(128 * 4);
  float* bpe = (float*)alloc(3 * 128 * 4);
  float* bpn = (float*)alloc(3 * 128 * 4);
  float* bde = (float*)alloc(16);

  // --- combine all MLP weight pairs (linear MLPs: W1@W2, b1@W2+b2), fp32 ---
  k_combine<<<(33 * 128 + 255) / 256, 256, 0, stream>>>(en_W1, en_b1, en_W2, en_b2, 32, 128, 128, Cen, ben);
  k_combine<<<(5 * 128 + 255) / 256, 256, 0, stream>>>(ee_W1, ee_b1, ee_W2, ee_b2, 4, 128, 128, Cee, bee);
  for (int s = 0; s < 3; ++s) {
    k_combine<<<(385 * 128 + 255) / 256, 256, 0, stream>>>(
        pe_W1 + (size_t)s * 384 * 128, pe_b1 + s * 128, pe_W2 + (size_t)s * 128 * 128, pe_b2 + s * 128,
        384, 128, 128, Cpe + (size_t)s * 384 * 128, bpe + s * 128);
    k_combine<<<(257 * 128 + 255) / 256, 256, 0, stream>>>(
        pn_W1 + (size_t)s * 256 * 128, pn_b1 + s * 128, pn_W2 + (size_t)s * 128 * 128, pn_b2 + s * 128,
        256, 128, 128, Cpn + (size_t)s * 256 * 128, bpn + s * 128);
  }
  k_combine<<<(129 * 3 + 255) / 256, 256, 0, stream>>>(de_W1, de_b1, de_W2, de_b2, 128, 128, 3, Cde, bde);
  k_pack16<<<(128 * 32 + 255) / 256, 256, 0, stream>>>(Cen, WenT, 32, 1);
  k_pack16<<<(3 * 384 * 128 + 255) / 256, 256, 0, stream>>>(Cpe, WpeT, 384, 3);
  k_pack16<<<(3 * 256 * 128 + 255) / 256, 256, 0, stream>>>(Cpn, WpnT, 256, 3);

  // --- CSR build: counts -> scan -> ticketed perm (edge slots sorted by recv) ---
  k_zeroi<<<(NN + 255) / 256, 256, 0, stream>>>(cnti, NN);
  k_counti<<<(NE + 255) / 256, 256, 0, stream>>>(recv, cnti);
  k_scan<<<1, 1024, 0, stream>>>(cnti, rownext, cntf);
  k_perm<<<(NE + 255) / 256, 256, 0, stream>>>(recv, rownext, perm);

  // --- init agg ---
  k_zero<<<((long)NN * D + 255) / 256, 256, 0, stream>>>(agg, (long)NN * D);

  // --- encode ---
  k_node_enc_m<<<(NN + 63) / 64, 256, 0, stream>>>(node_feat, WenT, ben, en_g, en_be, x);
  k_edge_enc<<<NE / 64, 256, 0, stream>>>(edge_feat, recv, perm, Cee, bee, ee_g, ee_be, e, agg);
  k_finalize<<<((long)NN * D + 255) / 256, 256, 0, stream>>>(x, agg, cntf);

  // --- process: 3 interaction-network steps ---
  for (int s = 0; s < 3; ++s) {
    k_edge_step_m<<<NE / 64, 256, 0, stream>>>(
        x, e, recv, send, perm, WpeT + (size_t)s * 128 * 384, bpe + s * 128,
        pe_g + s * 128, pe_be + s * 128, agg);
    k_node_step_m<<<(NN + 63) / 64, 256, 0, stream>>>(
        x, agg, cntf, WpnT + (size_t)s * 128 * 256, bpn + s * 128,
        pn_g + s * 128, pn_be + s * 128);
  }

  // --- decode ---
  k_decode<<<(NN + 255) / 256, 256, 0, stream>>>(x, Cde, bde, (float*)d_out);
}